// Round 14
// baseline (444.914 us; speedup 1.0000x reference)
//
#include <hip/hip_runtime.h>
#include <hip/hip_bf16.h>
#include <math.h>
#include <limits.h>

// Problem constants
#define NROWS 65536
#define DIM   256
#define NCODE 8192
#define NTOPK 5

typedef __attribute__((ext_vector_type(4))) float     f32x4;
typedef __attribute__((ext_vector_type(4))) int       i32x4;

// ---- workspace layout (bytes) ----
#define WS_ESWZ   0u          // i8 swizzled embed: 8192*256        = 2097152
#define WS_CINIT  2097152u    // i32 key-init: -(||16e||^2/2)*8192+code = 32768
#define WS_XQ     2129920u    // i8 x fragments [65536*256]         = 16777216 (dead after gemm)
#define WS_NEWEMB 2129920u    //   aliases XQ[0..8MB)   (embsum, after xq dead)
#define WS_ENTR   10518528u   //   aliases XQ[8MB..10.6MB) (entries)
#define WS_IDX5   18907136u   // i32 [65536*5]                      = 1310720
#define WS_W5     20217856u   // f32 [65536*5]                      = 1310720
#define WS_ENCSUM 21528576u   // f32 [8192]                         = 32768
#define WS_CNT    21561344u   // u32 [8192]                         = 32768
#define WS_OFFS   21594112u   // u32 [8192]                         = 32768
#define WS_CURS   21626880u   // u32 [8192]                         = 32768
#define WS_SFAC   21659648u   // f32 scalars                        = 256
// total ~20.7 MB   (candk[65536][64] i32 = 16MB lives in d_out, overwritten by k_quant)

#define ENT_PER_BLK 64
#define NENT (NROWS * NTOPK)

__device__ __forceinline__ void gl_lds16(const void* g, void* l) {
  __builtin_amdgcn_global_load_lds(
      (const __attribute__((address_space(1))) unsigned int*)g,
      (__attribute__((address_space(3))) unsigned int*)l, 16, 0, 0);
}

// monotonic u32 key for f32 (ascending float <-> ascending unsigned)
__device__ __forceinline__ unsigned f2key(float f) {
  unsigned u = __float_as_uint(f);
  return (u & 0x80000000u) ? ~u : (u | 0x80000000u);
}
__device__ __forceinline__ float key2f(unsigned k) {
  unsigned u = (k & 0x80000000u) ? (k ^ 0x80000000u) : ~k;
  return __uint_as_float(u);
}

__device__ __forceinline__ int pk4(f32x4 v) {
  int r = 0;
  #pragma unroll
  for (int j = 0; j < 4; ++j) {
    float q = fminf(127.f, fmaxf(-127.f, rintf(16.f * v[j])));
    r |= ((int)q & 255) << (8 * j);
  }
  return r;
}

// ============ K0 (fused): embed -> swizzled i8 + key-init  AND  x -> i8 frags ============
// blocks [0, NCODE): codebook prep; blocks [NCODE, NCODE+NROWS/64): x quantize.
__global__ __launch_bounds__(256) void k_prepall(const float* __restrict__ embed,
                                                 const float* __restrict__ x,
                                                 signed char* __restrict__ eswz,
                                                 int* __restrict__ cinit,
                                                 signed char* __restrict__ xq) {
  if (blockIdx.x < NCODE) {
    const int code = blockIdx.x;
    const int d = threadIdx.x;
    float v = embed[code * DIM + d];
    float qf = fminf(127.f, fmaxf(-127.f, rintf(16.f * v)));
    int q = (int)qf;
    __shared__ unsigned char rb[256];
    __shared__ int red[4];
    rb[d] = (unsigned char)(q & 255);
    int e2 = q * q;
    #pragma unroll
    for (int off = 32; off; off >>= 1) e2 += __shfl_down(e2, off);
    const int lane = d & 63, w = d >> 6;
    if (lane == 0) red[w] = e2;
    __syncthreads();
    if (d == 0) {
      int s = red[0] + red[1] + red[2] + red[3];
      cinit[code] = -(s >> 1) * 8192 + code;   // key-init: fold norm, shift, code
    }
    if (d < 64) {
      unsigned u = (unsigned)rb[4 * d] | ((unsigned)rb[4 * d + 1] << 8) |
                   ((unsigned)rb[4 * d + 2] << 16) | ((unsigned)rb[4 * d + 3] << 24);
      const int cs = (d >> 2) ^ (code & 15);   // XOR-swizzle 16B chunks within 256B row
      ((unsigned*)(eswz + code * 256))[(cs << 2) | (d & 3)] = u;
    }
  } else {
    // x -> i8 B-fragment layout; group g = 16 rows:
    // xq[g*4096 + (s*64 + q*16 + ln)*16] = row (g*16+ln), k in [64s+16q, +16).
    const int t = threadIdx.x;
    const int s = t >> 6, q = (t >> 4) & 3, ln = t & 15;
    const unsigned row0 = (blockIdx.x - NCODE) * 64;
    #pragma unroll
    for (int g = 0; g < 4; ++g) {
      const unsigned row = row0 + g * 16 + ln;
      const float* xr = x + row * DIM + s * 64 + q * 16;
      i32x4 dw;
      #pragma unroll
      for (int d = 0; d < 4; ++d) dw[d] = pk4(*(const f32x4*)(xr + d * 4));
      *(i32x4*)(xq + (unsigned)(row0 + g * 16) * 256u + (unsigned)t * 16u) = dw;
    }
  }
}

// ============ K1: i8-MFMA score GEMM, R=4/D=2 ring, 4-way code split ============
// (round-10/13 configuration: 174 us measured, VGPR=56, no spill)
// key = acc*8192 + cinit[code]  (cinit pre-folds -||e||^2/2, <<13, +global code)

struct PList { int a, b, c, d; };

__device__ __forceinline__ void ladder(PList& P, int t) {
  int c0 = min(P.a, t); P.a = max(P.a, t);
  int c1 = min(P.b, c0); P.b = max(P.b, c0);
  int c2 = min(P.c, c1); P.c = max(P.c, c1);
  P.d = max(P.d, c2);
}

__device__ __forceinline__ void psel(PList& P, i32x4 acc, i32x4 en) {
  int p0 = acc[0] * 8192 + en[0];
  int p1 = acc[1] * 8192 + en[1];
  int p2 = acc[2] * 8192 + en[2];
  int p3 = acc[3] * 8192 + en[3];
  int h1 = max(p0, p1);
  int h2 = max(p2, p3);
  int t1 = max(h1, h2);
  if (__any(t1 > P.d)) {                   // wave-uniform early-out (exact)
    int l1 = min(p0, p1), l2 = min(p2, p3);
    int t2 = max(min(h1, h2), max(l1, l2));
    ladder(P, t1);
    if (__any(t2 > P.d)) ladder(P, t2);    // rare: 2 top-4 codes in same 4-pack
  }
}

// one iteration; SL/NS compile-time (NS=(IT+2)&3).  Ring R=4, D=2: write slot
// never collides with reader slots (tile IT: +2, laggards at IT-1: +3 mod 4).
// vmcnt(8) = two iterations' staging (2 glds + 2 en each) may stay in flight.
#define GBODY(IT, SL, NS)                                                      \
  {                                                                            \
    const int tg = ((IT) + 2 < 64) ? (IT) + 2 : 63;                            \
    const signed char* src = esw_h + (unsigned)tg * 8192u;                     \
    gl_lds16(src + tid * 16, &ebuf[NS][tid * 16]);                             \
    gl_lds16(src + 4096 + tid * 16, &ebuf[NS][4096 + tid * 16]);               \
    i32x4 enC0 = *(const i32x4*)(cin_h + tg * 32 + q * 4);                     \
    i32x4 enC1 = *(const i32x4*)(cin_h + tg * 32 + 16 + q * 4);                \
    asm volatile("s_waitcnt vmcnt(8)\n\ts_barrier" ::: "memory");              \
    const signed char* eb = ebuf[SL];                                          \
    i32x4 a00 = {0, 0, 0, 0}, a01 = a00, a10 = a00, a11 = a00;                 \
    __builtin_amdgcn_s_setprio(1);                                             \
    _Pragma("unroll")                                                          \
    for (int s = 0; s < 4; ++s) {                                              \
      const int chunk = (4 * s + q) ^ ln;                                      \
      i32x4 ea0 = *(const i32x4*)&eb[ln * 256 + chunk * 16];                   \
      i32x4 ea1 = *(const i32x4*)&eb[4096 + ln * 256 + chunk * 16];            \
      a00 = __builtin_amdgcn_mfma_i32_16x16x64_i8(ea0, xf[0][s], a00, 0, 0, 0);\
      a10 = __builtin_amdgcn_mfma_i32_16x16x64_i8(ea0, xf[1][s], a10, 0, 0, 0);\
      a01 = __builtin_amdgcn_mfma_i32_16x16x64_i8(ea1, xf[0][s], a01, 0, 0, 0);\
      a11 = __builtin_amdgcn_mfma_i32_16x16x64_i8(ea1, xf[1][s], a11, 0, 0, 0);\
    }                                                                          \
    __builtin_amdgcn_s_setprio(0);                                             \
    psel(P0, a00, enA0); psel(P0, a01, enA1);                                  \
    psel(P1, a10, enA0); psel(P1, a11, enA1);                                  \
    enA0 = enB0; enA1 = enB1; enB0 = enC0; enB1 = enC1;                        \
  }

__global__ __launch_bounds__(256, 4) void k_gemm(const signed char* __restrict__ xq,
                                                 const signed char* __restrict__ eswz,
                                                 const int* __restrict__ cinit,
                                                 int* __restrict__ candk) {
  __shared__ signed char ebuf[4][8192];      // ring: 4 slots x (32 codes x 256 k i8) = 32KB
  const int tid = threadIdx.x;
  const int lane = tid & 63, wave = tid >> 6;
  const int q = lane >> 4, ln = lane & 15;
  const int quarter = blockIdx.x & 3, rblk = blockIdx.x >> 2;
  const int wrow0 = rblk * 128 + wave * 32;           // 32 rows per wave
  const signed char* esw_h = eswz + (unsigned)quarter * (2048u * 256u);
  const int* cin_h = cinit + quarter * 2048;

  // prologue: stage tiles 0,1 into slots 0,1; en pipeline depth 2
  gl_lds16(esw_h + tid * 16, &ebuf[0][tid * 16]);
  gl_lds16(esw_h + 4096 + tid * 16, &ebuf[0][4096 + tid * 16]);
  gl_lds16(esw_h + 8192 + tid * 16, &ebuf[1][tid * 16]);
  gl_lds16(esw_h + 8192 + 4096 + tid * 16, &ebuf[1][4096 + tid * 16]);
  i32x4 enA0 = *(const i32x4*)(cin_h + q * 4);
  i32x4 enA1 = *(const i32x4*)(cin_h + 16 + q * 4);
  i32x4 enB0 = *(const i32x4*)(cin_h + 32 + q * 4);
  i32x4 enB1 = *(const i32x4*)(cin_h + 48 + q * 4);

  // x fragments from pre-quantized coalesced layout: 1KB contiguous per load
  i32x4 xf[2][4];
  {
    const signed char* xb = xq + (unsigned)wrow0 * 256u;
    #pragma unroll
    for (int t = 0; t < 2; ++t)
      #pragma unroll
      for (int s = 0; s < 4; ++s)
        xf[t][s] = *(const i32x4*)(xb + t * 4096 + s * 1024 + lane * 16);
  }

  PList P0 = {INT_MIN, INT_MIN, INT_MIN, INT_MIN};   // row stream 0
  PList P1 = P0;                                     // row stream 1

  #pragma unroll 1
  for (int ob = 0; ob < 16; ++ob) {
    const int it0 = ob * 4;
    GBODY(it0 + 0, 0, 2)
    GBODY(it0 + 1, 1, 3)
    GBODY(it0 + 2, 2, 0)
    GBODY(it0 + 3, 3, 1)
  }

  // write 4 raw keys per (row, class=(quarter,q)); code = key & 8191
  {
    const int row0 = wrow0 + ln;
    i32x4 pk0 = {P0.a, P0.b, P0.c, P0.d};
    *(i32x4*)&candk[row0 * 64 + quarter * 16 + q * 4] = pk0;
    const int row1 = wrow0 + 16 + ln;
    i32x4 pk1 = {P1.a, P1.b, P1.c, P1.d};
    *(i32x4*)&candk[row1 * 64 + quarter * 16 + q * 4] = pk1;
  }
}

// ============ K2: two-stage refine: approx top-8 of 64 keys, exact re-score ============
__global__ __launch_bounds__(256) void k_refine(const float* __restrict__ x,
                                                const float* __restrict__ embed,
                                                const int* __restrict__ candk,
                                                float* __restrict__ out_idx,
                                                int* __restrict__ idx5,
                                                float* __restrict__ w5,
                                                float* __restrict__ enc_sum,
                                                unsigned* __restrict__ cnt) {
  __shared__ float sh[4][8][66];                        // 8.25KB
  const int wave = threadIdx.x >> 6, l = threadIdx.x & 63;
  const int row = blockIdx.x * 4 + wave;

  // ---- stage 1: approx top-8 of the 64 keys (register-only, full wave) ----
  int k = candk[row * 64 + l];
  int cd[8];
  #pragma unroll
  for (int j = 0; j < 8; ++j) {
    int m = k;
    #pragma unroll
    for (int off = 1; off < 64; off <<= 1) m = max(m, __shfl_xor(m, off));
    cd[j] = m & 8191;                                   // code of j-th best approx
    if (k == m) k = INT_MIN;                            // retire winner (keys unique)
  }

  // ---- stage 2: exact f32/f64 re-score of 8 candidates ----
  const float* xr = x + (unsigned)row * DIM;
  const f32x4 xv = *(const f32x4*)(xr + 4 * l);         // lane owns dims 4l..4l+3
  const float t0 = -2.f * xv[0], t1 = -2.f * xv[1];
  const float t2 = -2.f * xv[2], t3 = -2.f * xv[3];

  #pragma unroll
  for (int ci = 0; ci < 8; ++ci) {
    const f32x4 e = *(const f32x4*)(embed + (unsigned)cd[ci] * DIM + 4 * l);
    float p = e[0] * (e[0] + t0);
    p = fmaf(e[1], e[1] + t1, p);
    p = fmaf(e[2], e[2] + t2, p);
    p = fmaf(e[3], e[3] + t3, p);
    sh[wave][ci][l] = p;
  }
  asm volatile("s_waitcnt lgkmcnt(0)" ::: "memory");

  // transpose-reduce: cand c = l>>3 summed by 8 lanes (sub = l&7), f64 accumulate
  const int c = l >> 3, sub = l & 7;
  const float* sp = &sh[wave][c][sub * 8];
  f32x4 v0 = *(const f32x4*)sp;
  f32x4 v1 = *(const f32x4*)(sp + 4);
  double s64 = (double)v0[0] + (double)v0[1] + (double)v0[2] + (double)v0[3]
             + (double)v1[0] + (double)v1[1] + (double)v1[2] + (double)v1[3];
  s64 += __shfl_xor(s64, 1);
  s64 += __shfl_xor(s64, 2);
  s64 += __shfl_xor(s64, 4);

  // broadcast: lane l gets score of cand (l&7)
  double sc = __shfl(s64, (l & 7) * 8);
  unsigned fkey = f2key((float)sc);
  const int myc = cd[l & 7];

  // exact top-5 within 8-lane groups (groups redundant)
  bool used = false;
  int codes[5]; float svals[5];
  #pragma unroll
  for (int j = 0; j < 5; ++j) {
    unsigned kk = used ? 0xFFFFFFFFu : fkey;
    unsigned mm = kk;
    #pragma unroll
    for (int off = 1; off < 8; off <<= 1) mm = min(mm, (unsigned)__shfl_xor((int)mm, off));
    int cc = (kk == mm) ? myc : 0x7FFFFFFF;             // ties -> lower code
    #pragma unroll
    for (int off = 1; off < 8; off <<= 1) cc = min(cc, __shfl_xor(cc, off));
    used = used || (myc == cc);
    codes[j] = cc;
    svals[j] = key2f(mm);
  }

  float ex[5], sum = 0.f;
  #pragma unroll
  for (int j = 0; j < 5; ++j) { ex[j] = expf(-(svals[j] - svals[0])); sum += ex[j]; }
  const float inv = 1.f / sum;

  if (l == 0) {
    out_idx[row] = (float)codes[0];
    #pragma unroll
    for (int j = 0; j < 5; ++j) {
      float w = ex[j] * inv;
      idx5[row * 5 + j] = codes[j];
      w5[row * 5 + j] = w;
      atomicAdd(&enc_sum[codes[j]], w);
      atomicAdd(&cnt[codes[j]], 1u);
    }
  }
}

// ============ K3: parallel scan counts -> CSR offsets, plus S factor ============
__global__ __launch_bounds__(256) void k_scan(const unsigned* __restrict__ cnt,
                                              unsigned* __restrict__ offs,
                                              unsigned* __restrict__ cursor,
                                              const float* __restrict__ enc_sum,
                                              const float* __restrict__ cluster_size,
                                              float* __restrict__ sfac) {
  __shared__ unsigned part[256];
  __shared__ double sred[256];
  const int t = threadIdx.x;
  unsigned s = 0;
  for (int i = 0; i < 32; ++i) s += cnt[t * 32 + i];
  part[t] = s;
  double ds = 0.0;
  for (int i = t; i < NCODE; i += 256)
    ds += 0.1 * (double)cluster_size[i] + 0.9 * (double)enc_sum[i];
  sred[t] = ds;
  __syncthreads();
  // Hillis-Steele inclusive scan of part[]
  #pragma unroll
  for (int off = 1; off < 256; off <<= 1) {
    unsigned v = (t >= off) ? part[t - off] : 0u;
    __syncthreads();
    part[t] += v;
    __syncthreads();
  }
  // tree-reduce sred[]
  #pragma unroll
  for (int off = 128; off; off >>= 1) {
    if (t < off) sred[t] += sred[t + off];
    __syncthreads();
  }
  if (t == 0) {
    double S = sred[0];
    sfac[0] = (float)(S / (S + (double)NCODE * 1e-5));
  }
  unsigned off0 = part[t] - s;   // exclusive prefix for this thread's 32 codes
  for (int i = 0; i < 32; ++i) {
    unsigned c = cnt[t * 32 + i];
    offs[t * 32 + i] = off0;
    cursor[t * 32 + i] = off0;
    off0 += c;
  }
}

// ============ K3b: fill CSR entries (meta = code<<16 | row) ============
__global__ __launch_bounds__(256) void k_fill(const int* __restrict__ idx5,
                                              const float* __restrict__ w5,
                                              unsigned* __restrict__ cursor,
                                              uint2* __restrict__ entries) {
  const int i = blockIdx.x * 256 + threadIdx.x;
  if (i >= NENT) return;
  const unsigned c = (unsigned)idx5[i];
  const float w = w5[i];
  const unsigned row = (unsigned)i / 5u;
  const unsigned slot = atomicAdd(&cursor[c], 1u);
  entries[slot] = make_uint2((c << 16) | row, __float_as_uint(w));
}

// ============ K4: wave-per-segment gather-accumulate, f32x4 lanes ============
// one wave owns 64 entries; lane owns dims 4l..4l+3 (16B/lane = 1KB/row/wave).
// entries pointer is wave-uniform -> scalar loads; no LDS, no block sync.
__global__ __launch_bounds__(256) void k_accum2(const float* __restrict__ x,
                                                const uint2* __restrict__ entries,
                                                float* __restrict__ embsum) {
  const int l = threadIdx.x & 63;
  const int wv = __builtin_amdgcn_readfirstlane(threadIdx.x >> 6);
  const unsigned seg = blockIdx.x * 4u + (unsigned)wv;
  const uint2* ep = entries + seg * ENT_PER_BLK;

  f32x4 acc = {0.f, 0.f, 0.f, 0.f};
  unsigned cur = ep[0].x >> 16;
  #pragma unroll 8
  for (int i = 0; i < ENT_PER_BLK; ++i) {
    const uint2 e = ep[i];
    const unsigned code = e.x >> 16;
    const unsigned row = e.x & 0xFFFFu;
    const float w = __uint_as_float(e.y);
    if (code != cur) {                       // wave-uniform branch
      float* dst = embsum + cur * DIM + 4 * l;
      atomicAdd(dst + 0, acc[0]);
      atomicAdd(dst + 1, acc[1]);
      atomicAdd(dst + 2, acc[2]);
      atomicAdd(dst + 3, acc[3]);
      acc[0] = acc[1] = acc[2] = acc[3] = 0.f;
      cur = code;
    }
    const f32x4 xv = *(const f32x4*)(x + row * DIM + 4 * l);
    acc[0] = fmaf(w, xv[0], acc[0]);
    acc[1] = fmaf(w, xv[1], acc[1]);
    acc[2] = fmaf(w, xv[2], acc[2]);
    acc[3] = fmaf(w, xv[3], acc[3]);
  }
  float* dst = embsum + cur * DIM + 4 * l;
  atomicAdd(dst + 0, acc[0]);
  atomicAdd(dst + 1, acc[1]);
  atomicAdd(dst + 2, acc[2]);
  atomicAdd(dst + 3, acc[3]);
}

// ============ K5: quantize with fused normalization ============
// out[row] = sum_j w_j * (0.1*embed_avg[c_j] + 0.9*embsum[c_j]) / cs[c_j]
// cs[c] = (0.1*cluster_size[c] + 0.9*enc_sum[c] + 1e-5) * sfac  (scalar per code)
__global__ __launch_bounds__(256) void k_quant(const int* __restrict__ idx5,
                                               const float* __restrict__ w5,
                                               const float* __restrict__ embsum,
                                               const float* __restrict__ embed_avg,
                                               const float* __restrict__ cluster_size,
                                               const float* __restrict__ enc_sum,
                                               const float* __restrict__ sfac,
                                               float* __restrict__ out) {
  const int l = threadIdx.x & 63, wv = threadIdx.x >> 6;
  const int rb = blockIdx.x * 16;
  const float sf = sfac[0];
  #pragma unroll
  for (int r = 0; r < 4; ++r) {
    const int row = rb + wv * 4 + r;
    f32x4 acc = {0.f, 0.f, 0.f, 0.f};
    #pragma unroll
    for (int j = 0; j < 5; ++j) {
      const int c = idx5[row * 5 + j];
      const float wg = w5[row * 5 + j];
      const float ncs = 0.1f * cluster_size[c] + 0.9f * enc_sum[c];
      const float inv = wg / ((ncs + 1e-5f) * sf);
      const f32x4 es = *(const f32x4*)(embsum + (unsigned)c * DIM + 4 * l);
      const f32x4 ea = *(const f32x4*)(embed_avg + (unsigned)c * DIM + 4 * l);
      acc[0] = fmaf(inv, fmaf(0.9f, es[0], 0.1f * ea[0]), acc[0]);
      acc[1] = fmaf(inv, fmaf(0.9f, es[1], 0.1f * ea[1]), acc[1]);
      acc[2] = fmaf(inv, fmaf(0.9f, es[2], 0.1f * ea[2]), acc[2]);
      acc[3] = fmaf(inv, fmaf(0.9f, es[3], 0.1f * ea[3]), acc[3]);
    }
    *(f32x4*)(out + (unsigned)row * DIM + 4 * l) = acc;
  }
}

extern "C" void kernel_launch(void* const* d_in, const int* in_sizes, int n_in,
                              void* d_out, int out_size, void* d_ws, size_t ws_size,
                              hipStream_t stream) {
  const float* x            = (const float*)d_in[0];   // [65536,256]
  const float* embed        = (const float*)d_in[1];   // [8192,256]
  const float* cluster_size = (const float*)d_in[2];   // [8192]
  // d_in[3] cluster_sum unused for outputs
  const float* embed_avg    = (const float*)d_in[4];   // [8192,256]

  char* w = (char*)d_ws;
  signed char*    eswz   = (signed char*)(w + WS_ESWZ);
  int*            cinit  = (int*)(w + WS_CINIT);
  signed char*    xq     = (signed char*)(w + WS_XQ);
  int*            idx5   = (int*)(w + WS_IDX5);
  float*          w5     = (float*)(w + WS_W5);
  float*          encsum = (float*)(w + WS_ENCSUM);
  unsigned*       cnt    = (unsigned*)(w + WS_CNT);
  unsigned*       offs   = (unsigned*)(w + WS_OFFS);
  unsigned*       curs   = (unsigned*)(w + WS_CURS);
  float*          sfac   = (float*)(w + WS_SFAC);
  float*          embsum = (float*)(w + WS_NEWEMB);    // aliases xq (dead after gemm)
  uint2*          entr   = (uint2*)(w + WS_ENTR);      // aliases xq+8MB

  float* out_q   = (float*)d_out;                 // [65536*256]
  float* out_idx = out_q + (size_t)NROWS * DIM;   // [65536] as float
  int*   candk   = (int*)d_out;                   // 16MB scratch in d_out; k_quant overwrites

  // zero enc_sum + cnt (adjacent 64KB)
  hipMemsetAsync(w + WS_ENCSUM, 0, 65536, stream);

  k_prepall<<<NCODE + NROWS / 64, 256, 0, stream>>>(embed, x, eswz, cinit, xq);
  k_gemm<<<NROWS / 128 * 4, 256, 0, stream>>>(xq, eswz, cinit, candk);
  // xq dead; zero embsum (aliases xq) before accumulation
  hipMemsetAsync(w + WS_NEWEMB, 0, (size_t)NCODE * DIM * 4, stream);
  k_refine<<<NROWS / 4, 256, 0, stream>>>(x, embed, candk, out_idx, idx5, w5, encsum, cnt);
  k_scan<<<1, 256, 0, stream>>>(cnt, offs, curs, encsum, cluster_size, sfac);
  k_fill<<<(NENT + 255) / 256, 256, 0, stream>>>(idx5, w5, curs, entr);
  k_accum2<<<NENT / ENT_PER_BLK / 4, 256, 0, stream>>>(x, entr, embsum);
  k_quant<<<NROWS / 16, 256, 0, stream>>>(idx5, w5, embsum, embed_avg,
                                          cluster_size, encsum, sfac, out_q);
}

// Round 15
// 426.651 us; speedup vs baseline: 1.0428x; 1.0428x over previous
//
#include <hip/hip_runtime.h>
#include <hip/hip_bf16.h>
#include <math.h>
#include <limits.h>

// Problem constants
#define NROWS 65536
#define DIM   256
#define NCODE 8192
#define NTOPK 5

typedef __attribute__((ext_vector_type(4))) float     f32x4;
typedef __attribute__((ext_vector_type(4))) int       i32x4;

// ---- workspace layout (bytes) ----
#define WS_ESWZ   0u          // i8 swizzled embed: 8192*256        = 2097152
#define WS_CINIT  2097152u    // i32 key-init: -(||16e||^2/2)*8192+code = 32768
#define WS_XQ     2129920u    // i8 x fragments [65536*256]         = 16777216 (dead after gemm)
#define WS_NEWEMB 2129920u    //   aliases XQ[0..8MB)   (embsum, after xq dead)
#define WS_ENTR   10518528u   //   aliases XQ[8MB..10.6MB) (entries)
#define WS_IDX5   18907136u   // i32 [65536*5]                      = 1310720
#define WS_W5     20217856u   // f32 [65536*5]                      = 1310720
#define WS_ENCSUM 21528576u   // f32 [8192]                         = 32768
#define WS_CNT    21561344u   // u32 [8192]                         = 32768
#define WS_OFFS   21594112u   // u32 [8192]                         = 32768
#define WS_CURS   21626880u   // u32 [8192]                         = 32768
#define WS_SFAC   21659648u   // f32 scalars                        = 256
// total ~20.7 MB   (candk[65536][64] i32 = 16MB lives in d_out, overwritten by k_quant)

#define ENT_PER_BLK 64
#define NENT (NROWS * NTOPK)

__device__ __forceinline__ void gl_lds16(const void* g, void* l) {
  __builtin_amdgcn_global_load_lds(
      (const __attribute__((address_space(1))) unsigned int*)g,
      (__attribute__((address_space(3))) unsigned int*)l, 16, 0, 0);
}

// monotonic u32 key for f32 (ascending float <-> ascending unsigned)
__device__ __forceinline__ unsigned f2key(float f) {
  unsigned u = __float_as_uint(f);
  return (u & 0x80000000u) ? ~u : (u | 0x80000000u);
}
__device__ __forceinline__ float key2f(unsigned k) {
  unsigned u = (k & 0x80000000u) ? (k ^ 0x80000000u) : ~k;
  return __uint_as_float(u);
}

__device__ __forceinline__ int pk4(f32x4 v) {
  int r = 0;
  #pragma unroll
  for (int j = 0; j < 4; ++j) {
    float q = fminf(127.f, fmaxf(-127.f, rintf(16.f * v[j])));
    r |= ((int)q & 255) << (8 * j);
  }
  return r;
}

// ============ K0 (fused): embed -> swizzled i8 + key-init  AND  x -> i8 frags ============
// blocks [0, NCODE): codebook prep; blocks [NCODE, NCODE+NROWS/64): x quantize.
__global__ __launch_bounds__(256) void k_prepall(const float* __restrict__ embed,
                                                 const float* __restrict__ x,
                                                 signed char* __restrict__ eswz,
                                                 int* __restrict__ cinit,
                                                 signed char* __restrict__ xq) {
  if (blockIdx.x < NCODE) {
    const int code = blockIdx.x;
    const int d = threadIdx.x;
    float v = embed[code * DIM + d];
    float qf = fminf(127.f, fmaxf(-127.f, rintf(16.f * v)));
    int q = (int)qf;
    __shared__ unsigned char rb[256];
    __shared__ int red[4];
    rb[d] = (unsigned char)(q & 255);
    int e2 = q * q;
    #pragma unroll
    for (int off = 32; off; off >>= 1) e2 += __shfl_down(e2, off);
    const int lane = d & 63, w = d >> 6;
    if (lane == 0) red[w] = e2;
    __syncthreads();
    if (d == 0) {
      int s = red[0] + red[1] + red[2] + red[3];
      cinit[code] = -(s >> 1) * 8192 + code;   // key-init: fold norm, shift, code
    }
    if (d < 64) {
      unsigned u = (unsigned)rb[4 * d] | ((unsigned)rb[4 * d + 1] << 8) |
                   ((unsigned)rb[4 * d + 2] << 16) | ((unsigned)rb[4 * d + 3] << 24);
      const int cs = (d >> 2) ^ (code & 15);   // XOR-swizzle 16B chunks within 256B row
      ((unsigned*)(eswz + code * 256))[(cs << 2) | (d & 3)] = u;
    }
  } else {
    // x -> i8 B-fragment layout; group g = 16 rows:
    // xq[g*4096 + (s*64 + q*16 + ln)*16] = row (g*16+ln), k in [64s+16q, +16).
    const int t = threadIdx.x;
    const int s = t >> 6, q = (t >> 4) & 3, ln = t & 15;
    const unsigned row0 = (blockIdx.x - NCODE) * 64;
    #pragma unroll
    for (int g = 0; g < 4; ++g) {
      const unsigned row = row0 + g * 16 + ln;
      const float* xr = x + row * DIM + s * 64 + q * 16;
      i32x4 dw;
      #pragma unroll
      for (int d = 0; d < 4; ++d) dw[d] = pk4(*(const f32x4*)(xr + d * 4));
      *(i32x4*)(xq + (unsigned)(row0 + g * 16) * 256u + (unsigned)t * 16u) = dw;
    }
  }
}

// ============ K1: i8-MFMA score GEMM, R=4/D=2 ring, 4-way code split ============
// (round-10/13 configuration: 174 us measured, VGPR=56, no spill)
// key = acc*8192 + cinit[code]  (cinit pre-folds -||e||^2/2, <<13, +global code)

struct PList { int a, b, c, d; };

__device__ __forceinline__ void ladder(PList& P, int t) {
  int c0 = min(P.a, t); P.a = max(P.a, t);
  int c1 = min(P.b, c0); P.b = max(P.b, c0);
  int c2 = min(P.c, c1); P.c = max(P.c, c1);
  P.d = max(P.d, c2);
}

__device__ __forceinline__ void psel(PList& P, i32x4 acc, i32x4 en) {
  int p0 = acc[0] * 8192 + en[0];
  int p1 = acc[1] * 8192 + en[1];
  int p2 = acc[2] * 8192 + en[2];
  int p3 = acc[3] * 8192 + en[3];
  int h1 = max(p0, p1);
  int h2 = max(p2, p3);
  int t1 = max(h1, h2);
  if (__any(t1 > P.d)) {                   // wave-uniform early-out (exact)
    int l1 = min(p0, p1), l2 = min(p2, p3);
    int t2 = max(min(h1, h2), max(l1, l2));
    ladder(P, t1);
    if (__any(t2 > P.d)) ladder(P, t2);    // rare: 2 top-4 codes in same 4-pack
  }
}

// one iteration; SL/NS compile-time (NS=(IT+2)&3).  Ring R=4, D=2: write slot
// never collides with reader slots (tile IT: +2, laggards at IT-1: +3 mod 4).
// vmcnt(8) = two iterations' staging (2 glds + 2 en each) may stay in flight.
#define GBODY(IT, SL, NS)                                                      \
  {                                                                            \
    const int tg = ((IT) + 2 < 64) ? (IT) + 2 : 63;                            \
    const signed char* src = esw_h + (unsigned)tg * 8192u;                     \
    gl_lds16(src + tid * 16, &ebuf[NS][tid * 16]);                             \
    gl_lds16(src + 4096 + tid * 16, &ebuf[NS][4096 + tid * 16]);               \
    i32x4 enC0 = *(const i32x4*)(cin_h + tg * 32 + q * 4);                     \
    i32x4 enC1 = *(const i32x4*)(cin_h + tg * 32 + 16 + q * 4);                \
    asm volatile("s_waitcnt vmcnt(8)\n\ts_barrier" ::: "memory");              \
    const signed char* eb = ebuf[SL];                                          \
    i32x4 a00 = {0, 0, 0, 0}, a01 = a00, a10 = a00, a11 = a00;                 \
    __builtin_amdgcn_s_setprio(1);                                             \
    _Pragma("unroll")                                                          \
    for (int s = 0; s < 4; ++s) {                                              \
      const int chunk = (4 * s + q) ^ ln;                                      \
      i32x4 ea0 = *(const i32x4*)&eb[ln * 256 + chunk * 16];                   \
      i32x4 ea1 = *(const i32x4*)&eb[4096 + ln * 256 + chunk * 16];            \
      a00 = __builtin_amdgcn_mfma_i32_16x16x64_i8(ea0, xf[0][s], a00, 0, 0, 0);\
      a10 = __builtin_amdgcn_mfma_i32_16x16x64_i8(ea0, xf[1][s], a10, 0, 0, 0);\
      a01 = __builtin_amdgcn_mfma_i32_16x16x64_i8(ea1, xf[0][s], a01, 0, 0, 0);\
      a11 = __builtin_amdgcn_mfma_i32_16x16x64_i8(ea1, xf[1][s], a11, 0, 0, 0);\
    }                                                                          \
    __builtin_amdgcn_s_setprio(0);                                             \
    psel(P0, a00, enA0); psel(P0, a01, enA1);                                  \
    psel(P1, a10, enA0); psel(P1, a11, enA1);                                  \
    enA0 = enB0; enA1 = enB1; enB0 = enC0; enB1 = enC1;                        \
  }

__global__ __launch_bounds__(256, 4) void k_gemm(const signed char* __restrict__ xq,
                                                 const signed char* __restrict__ eswz,
                                                 const int* __restrict__ cinit,
                                                 int* __restrict__ candk) {
  __shared__ signed char ebuf[4][8192];      // ring: 4 slots x (32 codes x 256 k i8) = 32KB
  const int tid = threadIdx.x;
  const int lane = tid & 63, wave = tid >> 6;
  const int q = lane >> 4, ln = lane & 15;
  const int quarter = blockIdx.x & 3, rblk = blockIdx.x >> 2;
  const int wrow0 = rblk * 128 + wave * 32;           // 32 rows per wave
  const signed char* esw_h = eswz + (unsigned)quarter * (2048u * 256u);
  const int* cin_h = cinit + quarter * 2048;

  // prologue: stage tiles 0,1 into slots 0,1; en pipeline depth 2
  gl_lds16(esw_h + tid * 16, &ebuf[0][tid * 16]);
  gl_lds16(esw_h + 4096 + tid * 16, &ebuf[0][4096 + tid * 16]);
  gl_lds16(esw_h + 8192 + tid * 16, &ebuf[1][tid * 16]);
  gl_lds16(esw_h + 8192 + 4096 + tid * 16, &ebuf[1][4096 + tid * 16]);
  i32x4 enA0 = *(const i32x4*)(cin_h + q * 4);
  i32x4 enA1 = *(const i32x4*)(cin_h + 16 + q * 4);
  i32x4 enB0 = *(const i32x4*)(cin_h + 32 + q * 4);
  i32x4 enB1 = *(const i32x4*)(cin_h + 48 + q * 4);

  // x fragments from pre-quantized coalesced layout: 1KB contiguous per load
  i32x4 xf[2][4];
  {
    const signed char* xb = xq + (unsigned)wrow0 * 256u;
    #pragma unroll
    for (int t = 0; t < 2; ++t)
      #pragma unroll
      for (int s = 0; s < 4; ++s)
        xf[t][s] = *(const i32x4*)(xb + t * 4096 + s * 1024 + lane * 16);
  }

  PList P0 = {INT_MIN, INT_MIN, INT_MIN, INT_MIN};   // row stream 0
  PList P1 = P0;                                     // row stream 1

  #pragma unroll 1
  for (int ob = 0; ob < 16; ++ob) {
    const int it0 = ob * 4;
    GBODY(it0 + 0, 0, 2)
    GBODY(it0 + 1, 1, 3)
    GBODY(it0 + 2, 2, 0)
    GBODY(it0 + 3, 3, 1)
  }

  // write 4 raw keys per (row, class=(quarter,q)); code = key & 8191
  {
    const int row0 = wrow0 + ln;
    i32x4 pk0 = {P0.a, P0.b, P0.c, P0.d};
    *(i32x4*)&candk[row0 * 64 + quarter * 16 + q * 4] = pk0;
    const int row1 = wrow0 + 16 + ln;
    i32x4 pk1 = {P1.a, P1.b, P1.c, P1.d};
    *(i32x4*)&candk[row1 * 64 + quarter * 16 + q * 4] = pk1;
  }
}

// ============ K2: two-stage refine: approx top-8 of 64 keys, exact re-score ============
__global__ __launch_bounds__(256) void k_refine(const float* __restrict__ x,
                                                const float* __restrict__ embed,
                                                const int* __restrict__ candk,
                                                float* __restrict__ out_idx,
                                                int* __restrict__ idx5,
                                                float* __restrict__ w5,
                                                float* __restrict__ enc_sum,
                                                unsigned* __restrict__ cnt) {
  __shared__ float sh[4][8][66];                        // 8.25KB
  const int wave = threadIdx.x >> 6, l = threadIdx.x & 63;
  const int row = blockIdx.x * 4 + wave;

  // ---- stage 1: approx top-8 of the 64 keys (register-only, full wave) ----
  int k = candk[row * 64 + l];
  int cd[8];
  #pragma unroll
  for (int j = 0; j < 8; ++j) {
    int m = k;
    #pragma unroll
    for (int off = 1; off < 64; off <<= 1) m = max(m, __shfl_xor(m, off));
    cd[j] = m & 8191;                                   // code of j-th best approx
    if (k == m) k = INT_MIN;                            // retire winner (keys unique)
  }

  // ---- stage 2: exact f32/f64 re-score of 8 candidates ----
  const float* xr = x + (unsigned)row * DIM;
  const f32x4 xv = *(const f32x4*)(xr + 4 * l);         // lane owns dims 4l..4l+3
  const float t0 = -2.f * xv[0], t1 = -2.f * xv[1];
  const float t2 = -2.f * xv[2], t3 = -2.f * xv[3];

  #pragma unroll
  for (int ci = 0; ci < 8; ++ci) {
    const f32x4 e = *(const f32x4*)(embed + (unsigned)cd[ci] * DIM + 4 * l);
    float p = e[0] * (e[0] + t0);
    p = fmaf(e[1], e[1] + t1, p);
    p = fmaf(e[2], e[2] + t2, p);
    p = fmaf(e[3], e[3] + t3, p);
    sh[wave][ci][l] = p;
  }
  asm volatile("s_waitcnt lgkmcnt(0)" ::: "memory");

  // transpose-reduce: cand c = l>>3 summed by 8 lanes (sub = l&7), f64 accumulate
  const int c = l >> 3, sub = l & 7;
  const float* sp = &sh[wave][c][sub * 8];
  f32x4 v0 = *(const f32x4*)sp;
  f32x4 v1 = *(const f32x4*)(sp + 4);
  double s64 = (double)v0[0] + (double)v0[1] + (double)v0[2] + (double)v0[3]
             + (double)v1[0] + (double)v1[1] + (double)v1[2] + (double)v1[3];
  s64 += __shfl_xor(s64, 1);
  s64 += __shfl_xor(s64, 2);
  s64 += __shfl_xor(s64, 4);

  // broadcast: lane l gets score of cand (l&7)
  double sc = __shfl(s64, (l & 7) * 8);
  unsigned fkey = f2key((float)sc);
  const int myc = cd[l & 7];

  // exact top-5 within 8-lane groups (groups redundant)
  bool used = false;
  int codes[5]; float svals[5];
  #pragma unroll
  for (int j = 0; j < 5; ++j) {
    unsigned kk = used ? 0xFFFFFFFFu : fkey;
    unsigned mm = kk;
    #pragma unroll
    for (int off = 1; off < 8; off <<= 1) mm = min(mm, (unsigned)__shfl_xor((int)mm, off));
    int cc = (kk == mm) ? myc : 0x7FFFFFFF;             // ties -> lower code
    #pragma unroll
    for (int off = 1; off < 8; off <<= 1) cc = min(cc, __shfl_xor(cc, off));
    used = used || (myc == cc);
    codes[j] = cc;
    svals[j] = key2f(mm);
  }

  float ex[5], sum = 0.f;
  #pragma unroll
  for (int j = 0; j < 5; ++j) { ex[j] = expf(-(svals[j] - svals[0])); sum += ex[j]; }
  const float inv = 1.f / sum;

  if (l == 0) {
    out_idx[row] = (float)codes[0];
    #pragma unroll
    for (int j = 0; j < 5; ++j) {
      float w = ex[j] * inv;
      idx5[row * 5 + j] = codes[j];
      w5[row * 5 + j] = w;
      atomicAdd(&enc_sum[codes[j]], w);
      atomicAdd(&cnt[codes[j]], 1u);
    }
  }
}

// ============ K3: parallel scan counts -> CSR offsets, plus S factor ============
__global__ __launch_bounds__(256) void k_scan(const unsigned* __restrict__ cnt,
                                              unsigned* __restrict__ offs,
                                              unsigned* __restrict__ cursor,
                                              const float* __restrict__ enc_sum,
                                              const float* __restrict__ cluster_size,
                                              float* __restrict__ sfac) {
  __shared__ unsigned part[256];
  __shared__ double sred[256];
  const int t = threadIdx.x;
  unsigned s = 0;
  for (int i = 0; i < 32; ++i) s += cnt[t * 32 + i];
  part[t] = s;
  double ds = 0.0;
  for (int i = t; i < NCODE; i += 256)
    ds += 0.1 * (double)cluster_size[i] + 0.9 * (double)enc_sum[i];
  sred[t] = ds;
  __syncthreads();
  // Hillis-Steele inclusive scan of part[]
  #pragma unroll
  for (int off = 1; off < 256; off <<= 1) {
    unsigned v = (t >= off) ? part[t - off] : 0u;
    __syncthreads();
    part[t] += v;
    __syncthreads();
  }
  // tree-reduce sred[]
  #pragma unroll
  for (int off = 128; off; off >>= 1) {
    if (t < off) sred[t] += sred[t + off];
    __syncthreads();
  }
  if (t == 0) {
    double S = sred[0];
    sfac[0] = (float)(S / (S + (double)NCODE * 1e-5));
  }
  unsigned off0 = part[t] - s;   // exclusive prefix for this thread's 32 codes
  for (int i = 0; i < 32; ++i) {
    unsigned c = cnt[t * 32 + i];
    offs[t * 32 + i] = off0;
    cursor[t * 32 + i] = off0;
    off0 += c;
  }
}

// ============ K3b: fill CSR entries (meta = code<<16 | row) ============
__global__ __launch_bounds__(256) void k_fill(const int* __restrict__ idx5,
                                              const float* __restrict__ w5,
                                              unsigned* __restrict__ cursor,
                                              uint2* __restrict__ entries) {
  const int i = blockIdx.x * 256 + threadIdx.x;
  if (i >= NENT) return;
  const unsigned c = (unsigned)idx5[i];
  const float w = w5[i];
  const unsigned row = (unsigned)i / 5u;
  const unsigned slot = atomicAdd(&cursor[c], 1u);
  entries[slot] = make_uint2((c << 16) | row, __float_as_uint(w));
}

// ============ K4: flat segmented gather-accumulate (load-balanced) ============
__global__ __launch_bounds__(256) void k_accum2(const float* __restrict__ x,
                                                const uint2* __restrict__ entries,
                                                float* __restrict__ embsum) {
  __shared__ uint2 ent[ENT_PER_BLK];
  const int t = threadIdx.x;
  const unsigned base = blockIdx.x * ENT_PER_BLK;
  if (t < ENT_PER_BLK * 2)
    ((unsigned*)ent)[t] = ((const unsigned*)(entries + base))[t];
  __syncthreads();

  float acc = 0.f;
  unsigned cur = ent[0].x >> 16;
  #pragma unroll 8
  for (int i = 0; i < ENT_PER_BLK; ++i) {
    const uint2 e = ent[i];
    const unsigned code = e.x >> 16;
    const unsigned row = e.x & 0xFFFFu;
    const float w = __uint_as_float(e.y);
    if (code != cur) {                       // block-uniform branch
      atomicAdd(&embsum[cur * DIM + t], acc);
      acc = 0.f; cur = code;
    }
    acc = fmaf(w, x[row * DIM + t], acc);
  }
  atomicAdd(&embsum[cur * DIM + t], acc);
}

// ============ K4b: normalize embsum -> new_embed (in place) ============
__global__ __launch_bounds__(256) void k_norm(const float* __restrict__ embed_avg,
                                              const float* __restrict__ cluster_size,
                                              const float* __restrict__ enc_sum,
                                              const float* __restrict__ sfac,
                                              float* __restrict__ embsum /* -> newemb */) {
  const int k = blockIdx.x, d = threadIdx.x;
  const float ncs = 0.1f * cluster_size[k] + 0.9f * enc_sum[k];
  const float cs = (ncs + 1e-5f) * sfac[0];
  const unsigned o = (unsigned)k * DIM + d;
  embsum[o] = (0.1f * embed_avg[o] + 0.9f * embsum[o]) / cs;
}

// ============ K5: quantize = sum_j w_j * new_embed[idx_j], f32x4 wide ============
__global__ __launch_bounds__(256) void k_quant(const int* __restrict__ idx5,
                                               const float* __restrict__ w5,
                                               const float* __restrict__ newemb,
                                               float* __restrict__ out) {
  const int l = threadIdx.x & 63, wv = threadIdx.x >> 6;
  const int rb = blockIdx.x * 16;
  #pragma unroll
  for (int r = 0; r < 4; ++r) {
    const int row = rb + wv * 4 + r;
    f32x4 acc = {0.f, 0.f, 0.f, 0.f};
    #pragma unroll
    for (int j = 0; j < 5; ++j) {
      const int c = idx5[row * 5 + j];
      const float wg = w5[row * 5 + j];
      const f32x4 e = *(const f32x4*)(newemb + (unsigned)c * DIM + 4 * l);
      acc[0] = fmaf(wg, e[0], acc[0]);
      acc[1] = fmaf(wg, e[1], acc[1]);
      acc[2] = fmaf(wg, e[2], acc[2]);
      acc[3] = fmaf(wg, e[3], acc[3]);
    }
    *(f32x4*)(out + (unsigned)row * DIM + 4 * l) = acc;
  }
}

extern "C" void kernel_launch(void* const* d_in, const int* in_sizes, int n_in,
                              void* d_out, int out_size, void* d_ws, size_t ws_size,
                              hipStream_t stream) {
  const float* x            = (const float*)d_in[0];   // [65536,256]
  const float* embed        = (const float*)d_in[1];   // [8192,256]
  const float* cluster_size = (const float*)d_in[2];   // [8192]
  // d_in[3] cluster_sum unused for outputs
  const float* embed_avg    = (const float*)d_in[4];   // [8192,256]

  char* w = (char*)d_ws;
  signed char*    eswz   = (signed char*)(w + WS_ESWZ);
  int*            cinit  = (int*)(w + WS_CINIT);
  signed char*    xq     = (signed char*)(w + WS_XQ);
  int*            idx5   = (int*)(w + WS_IDX5);
  float*          w5     = (float*)(w + WS_W5);
  float*          encsum = (float*)(w + WS_ENCSUM);
  unsigned*       cnt    = (unsigned*)(w + WS_CNT);
  unsigned*       offs   = (unsigned*)(w + WS_OFFS);
  unsigned*       curs   = (unsigned*)(w + WS_CURS);
  float*          sfac   = (float*)(w + WS_SFAC);
  float*          embsum = (float*)(w + WS_NEWEMB);    // aliases xq (dead after gemm)
  uint2*          entr   = (uint2*)(w + WS_ENTR);      // aliases xq+8MB

  float* out_q   = (float*)d_out;                 // [65536*256]
  float* out_idx = out_q + (size_t)NROWS * DIM;   // [65536] as float
  int*   candk   = (int*)d_out;                   // 16MB scratch in d_out; k_quant overwrites

  // zero enc_sum + cnt (adjacent 64KB)
  hipMemsetAsync(w + WS_ENCSUM, 0, 65536, stream);

  k_prepall<<<NCODE + NROWS / 64, 256, 0, stream>>>(embed, x, eswz, cinit, xq);
  k_gemm<<<NROWS / 128 * 4, 256, 0, stream>>>(xq, eswz, cinit, candk);
  // xq dead; zero embsum (aliases xq) before accumulation
  hipMemsetAsync(w + WS_NEWEMB, 0, (size_t)NCODE * DIM * 4, stream);
  k_refine<<<NROWS / 4, 256, 0, stream>>>(x, embed, candk, out_idx, idx5, w5, encsum, cnt);
  k_scan<<<1, 256, 0, stream>>>(cnt, offs, curs, encsum, cluster_size, sfac);
  k_fill<<<(NENT + 255) / 256, 256, 0, stream>>>(idx5, w5, curs, entr);
  k_accum2<<<NENT / ENT_PER_BLK, 256, 0, stream>>>(x, entr, embsum);
  k_norm<<<NCODE, 256, 0, stream>>>(embed_avg, cluster_size, encsum, sfac, embsum);
  k_quant<<<NROWS / 16, 256, 0, stream>>>(idx5, w5, embsum, out_q);
}

// Round 16
// 422.234 us; speedup vs baseline: 1.0537x; 1.0105x over previous
//
#include <hip/hip_runtime.h>
#include <hip/hip_bf16.h>
#include <math.h>
#include <limits.h>

// Problem constants
#define NROWS 65536
#define DIM   256
#define NCODE 8192
#define NTOPK 5

typedef __attribute__((ext_vector_type(4))) float     f32x4;
typedef __attribute__((ext_vector_type(4))) int       i32x4;

// ---- workspace layout (bytes) ----
#define WS_ESWZ   0u          // i8 swizzled embed: 8192*256        = 2097152
#define WS_CINIT  2097152u    // i32 key-init: -(||16e||^2/2)*8192+code = 32768
#define WS_XQ     2129920u    // i8 x fragments [65536*256]         = 16777216 (dead after gemm)
#define WS_NEWEMB 2129920u    //   aliases XQ[0..8MB)   (embsum, after xq dead)
#define WS_ENTR   10518528u   //   aliases XQ[8MB..10.6MB) (entries)
#define WS_IDX5   18907136u   // i32 [65536*5]                      = 1310720
#define WS_W5     20217856u   // f32 [65536*5]                      = 1310720
#define WS_ENCSUM 21528576u   // f32 [8192]                         = 32768
#define WS_CNT    21561344u   // u32 [8192]                         = 32768
#define WS_OFFS   21594112u   // u32 [8192]                         = 32768
#define WS_CURS   21626880u   // u32 [8192]                         = 32768
#define WS_SFAC   21659648u   // f32 scalars                        = 256
// total ~20.7 MB   (candk[65536][64] i32 = 16MB lives in d_out, overwritten by k_quant)

#define ENT_PER_BLK 64
#define NENT (NROWS * NTOPK)

__device__ __forceinline__ void gl_lds16(const void* g, void* l) {
  __builtin_amdgcn_global_load_lds(
      (const __attribute__((address_space(1))) unsigned int*)g,
      (__attribute__((address_space(3))) unsigned int*)l, 16, 0, 0);
}

// monotonic u32 key for f32 (ascending float <-> ascending unsigned)
__device__ __forceinline__ unsigned f2key(float f) {
  unsigned u = __float_as_uint(f);
  return (u & 0x80000000u) ? ~u : (u | 0x80000000u);
}
__device__ __forceinline__ float key2f(unsigned k) {
  unsigned u = (k & 0x80000000u) ? (k ^ 0x80000000u) : ~k;
  return __uint_as_float(u);
}

__device__ __forceinline__ int pk4(f32x4 v) {
  int r = 0;
  #pragma unroll
  for (int j = 0; j < 4; ++j) {
    float q = fminf(127.f, fmaxf(-127.f, rintf(16.f * v[j])));
    r |= ((int)q & 255) << (8 * j);
  }
  return r;
}

// ============ K0 (fused): embed -> swizzled i8 + key-init  AND  x -> i8 frags ============
// blocks [0, NCODE): codebook prep; blocks [NCODE, NCODE+NROWS/64): x quantize.
__global__ __launch_bounds__(256) void k_prepall(const float* __restrict__ embed,
                                                 const float* __restrict__ x,
                                                 signed char* __restrict__ eswz,
                                                 int* __restrict__ cinit,
                                                 signed char* __restrict__ xq) {
  if (blockIdx.x < NCODE) {
    const int code = blockIdx.x;
    const int d = threadIdx.x;
    float v = embed[code * DIM + d];
    float qf = fminf(127.f, fmaxf(-127.f, rintf(16.f * v)));
    int q = (int)qf;
    __shared__ unsigned char rb[256];
    __shared__ int red[4];
    rb[d] = (unsigned char)(q & 255);
    int e2 = q * q;
    #pragma unroll
    for (int off = 32; off; off >>= 1) e2 += __shfl_down(e2, off);
    const int lane = d & 63, w = d >> 6;
    if (lane == 0) red[w] = e2;
    __syncthreads();
    if (d == 0) {
      int s = red[0] + red[1] + red[2] + red[3];
      cinit[code] = -(s >> 1) * 8192 + code;   // key-init: fold norm, shift, code
    }
    if (d < 64) {
      unsigned u = (unsigned)rb[4 * d] | ((unsigned)rb[4 * d + 1] << 8) |
                   ((unsigned)rb[4 * d + 2] << 16) | ((unsigned)rb[4 * d + 3] << 24);
      const int cs = (d >> 2) ^ (code & 15);   // XOR-swizzle 16B chunks within 256B row
      ((unsigned*)(eswz + code * 256))[(cs << 2) | (d & 3)] = u;
    }
  } else {
    // x -> i8 B-fragment layout; group g = 16 rows:
    // xq[g*4096 + (s*64 + q*16 + ln)*16] = row (g*16+ln), k in [64s+16q, +16).
    const int t = threadIdx.x;
    const int s = t >> 6, q = (t >> 4) & 3, ln = t & 15;
    const unsigned row0 = (blockIdx.x - NCODE) * 64;
    #pragma unroll
    for (int g = 0; g < 4; ++g) {
      const unsigned row = row0 + g * 16 + ln;
      const float* xr = x + row * DIM + s * 64 + q * 16;
      i32x4 dw;
      #pragma unroll
      for (int d = 0; d < 4; ++d) dw[d] = pk4(*(const f32x4*)(xr + d * 4));
      *(i32x4*)(xq + (unsigned)(row0 + g * 16) * 256u + (unsigned)t * 16u) = dw;
    }
  }
}

// ============ K1: i8-MFMA score GEMM, R=3/D=1 ring, 24KB LDS, (256,4) bound ============
// key = acc*8192 + cinit[code]  (cinit pre-folds -||e||^2/2, <<13, +global code)

struct PList { int a, b, c, d; };

__device__ __forceinline__ void ladder(PList& P, int t) {
  int c0 = min(P.a, t); P.a = max(P.a, t);
  int c1 = min(P.b, c0); P.b = max(P.b, c0);
  int c2 = min(P.c, c1); P.c = max(P.c, c1);
  P.d = max(P.d, c2);
}

__device__ __forceinline__ void psel(PList& P, i32x4 acc, i32x4 en) {
  int p0 = acc[0] * 8192 + en[0];
  int p1 = acc[1] * 8192 + en[1];
  int p2 = acc[2] * 8192 + en[2];
  int p3 = acc[3] * 8192 + en[3];
  int h1 = max(p0, p1);
  int h2 = max(p2, p3);
  int t1 = max(h1, h2);
  if (__any(t1 > P.d)) {                   // wave-uniform early-out (exact)
    int l1 = min(p0, p1), l2 = min(p2, p3);
    int t2 = max(min(h1, h2), max(l1, l2));
    ladder(P, t1);
    if (__any(t2 > P.d)) ladder(P, t2);    // rare: 2 top-4 codes in same 4-pack
  }
}

// one iteration; SL/NS compile-time (NS=(IT+1)%3, D=1).  ENC = en regs for
// tile IT (loaded one iter earlier), ENN = filled for tile IT+1 (A/B
// alternation -> no rotation movs).  Ring R=3, D=1 race-free: between
// consecutive barriers, in-flight writes target slots (IT+1)%3 / (IT+2)%3
// while reads touch IT%3 only.  vmcnt(4) = this iter's 2 glds + 2 en loads
// may remain outstanding; the prior iter's staging (slot IT%3) is complete.
#define GBODY(IT, SL, NS, ENC, ENN)                                            \
  {                                                                            \
    const int tn = ((IT) + 1 < 64) ? (IT) + 1 : 63;                            \
    const signed char* src = esw_h + (unsigned)tn * 8192u;                     \
    gl_lds16(src + tid * 16, &ebuf[NS][tid * 16]);                             \
    gl_lds16(src + 4096 + tid * 16, &ebuf[NS][4096 + tid * 16]);               \
    ENN##0 = *(const i32x4*)(cin_h + tn * 32 + q * 4);                         \
    ENN##1 = *(const i32x4*)(cin_h + tn * 32 + 16 + q * 4);                    \
    asm volatile("s_waitcnt vmcnt(4)\n\ts_barrier" ::: "memory");              \
    const signed char* eb = ebuf[SL];                                          \
    i32x4 a00 = {0, 0, 0, 0}, a01 = a00, a10 = a00, a11 = a00;                 \
    __builtin_amdgcn_s_setprio(1);                                             \
    _Pragma("unroll")                                                          \
    for (int s = 0; s < 4; ++s) {                                              \
      const int chunk = (4 * s + q) ^ ln;                                      \
      i32x4 ea0 = *(const i32x4*)&eb[ln * 256 + chunk * 16];                   \
      i32x4 ea1 = *(const i32x4*)&eb[4096 + ln * 256 + chunk * 16];            \
      a00 = __builtin_amdgcn_mfma_i32_16x16x64_i8(ea0, xf[0][s], a00, 0, 0, 0);\
      a10 = __builtin_amdgcn_mfma_i32_16x16x64_i8(ea0, xf[1][s], a10, 0, 0, 0);\
      a01 = __builtin_amdgcn_mfma_i32_16x16x64_i8(ea1, xf[0][s], a01, 0, 0, 0);\
      a11 = __builtin_amdgcn_mfma_i32_16x16x64_i8(ea1, xf[1][s], a11, 0, 0, 0);\
    }                                                                          \
    __builtin_amdgcn_s_setprio(0);                                             \
    psel(P0, a00, ENC##0); psel(P0, a01, ENC##1);                              \
    psel(P1, a10, ENC##0); psel(P1, a11, ENC##1);                              \
  }

__global__ __launch_bounds__(256, 4) void k_gemm(const signed char* __restrict__ xq,
                                                 const signed char* __restrict__ eswz,
                                                 const int* __restrict__ cinit,
                                                 int* __restrict__ candk) {
  __shared__ signed char ebuf[3][8192];      // ring: 3 slots x (32 codes x 256 k i8) = 24KB
  const int tid = threadIdx.x;
  const int lane = tid & 63, wave = tid >> 6;
  const int q = lane >> 4, ln = lane & 15;
  const int quarter = blockIdx.x & 3, rblk = blockIdx.x >> 2;
  const int wrow0 = rblk * 128 + wave * 32;           // 32 rows per wave
  const signed char* esw_h = eswz + (unsigned)quarter * (2048u * 256u);
  const int* cin_h = cinit + quarter * 2048;

  // prologue: stage tile 0 into slot 0; en for tile 0 into A set
  gl_lds16(esw_h + tid * 16, &ebuf[0][tid * 16]);
  gl_lds16(esw_h + 4096 + tid * 16, &ebuf[0][4096 + tid * 16]);
  i32x4 enA0 = *(const i32x4*)(cin_h + q * 4);
  i32x4 enA1 = *(const i32x4*)(cin_h + 16 + q * 4);
  i32x4 enB0 = {0, 0, 0, 0}, enB1 = {0, 0, 0, 0};

  // x fragments from pre-quantized coalesced layout: 1KB contiguous per load
  i32x4 xf[2][4];
  {
    const signed char* xb = xq + (unsigned)wrow0 * 256u;
    #pragma unroll
    for (int t = 0; t < 2; ++t)
      #pragma unroll
      for (int s = 0; s < 4; ++s)
        xf[t][s] = *(const i32x4*)(xb + t * 4096 + s * 1024 + lane * 16);
  }

  PList P0 = {INT_MIN, INT_MIN, INT_MIN, INT_MIN};   // row stream 0
  PList P1 = P0;                                     // row stream 1

  // 64 iters = 10 x 6-wide (even en parity, slots 0,1,2,0,1,2) + 4 tail
  #pragma unroll 1
  for (int ob = 0; ob < 10; ++ob) {
    const int it0 = ob * 6;
    GBODY(it0 + 0, 0, 1, enA, enB)
    GBODY(it0 + 1, 1, 2, enB, enA)
    GBODY(it0 + 2, 2, 0, enA, enB)
    GBODY(it0 + 3, 0, 1, enB, enA)
    GBODY(it0 + 4, 1, 2, enA, enB)
    GBODY(it0 + 5, 2, 0, enB, enA)
  }
  GBODY(60, 0, 1, enA, enB)
  GBODY(61, 1, 2, enB, enA)
  GBODY(62, 2, 0, enA, enB)
  GBODY(63, 0, 1, enB, enA)

  // write 4 raw keys per (row, class=(quarter,q)); code = key & 8191
  {
    const int row0 = wrow0 + ln;
    i32x4 pk0 = {P0.a, P0.b, P0.c, P0.d};
    *(i32x4*)&candk[row0 * 64 + quarter * 16 + q * 4] = pk0;
    const int row1 = wrow0 + 16 + ln;
    i32x4 pk1 = {P1.a, P1.b, P1.c, P1.d};
    *(i32x4*)&candk[row1 * 64 + quarter * 16 + q * 4] = pk1;
  }
}

// ============ K2: two-stage refine: approx top-8 of 64 keys, exact re-score ============
__global__ __launch_bounds__(256) void k_refine(const float* __restrict__ x,
                                                const float* __restrict__ embed,
                                                const int* __restrict__ candk,
                                                float* __restrict__ out_idx,
                                                int* __restrict__ idx5,
                                                float* __restrict__ w5,
                                                float* __restrict__ enc_sum,
                                                unsigned* __restrict__ cnt) {
  __shared__ float sh[4][8][66];                        // 8.25KB
  const int wave = threadIdx.x >> 6, l = threadIdx.x & 63;
  const int row = blockIdx.x * 4 + wave;

  // ---- stage 1: approx top-8 of the 64 keys (register-only, full wave) ----
  int k = candk[row * 64 + l];
  int cd[8];
  #pragma unroll
  for (int j = 0; j < 8; ++j) {
    int m = k;
    #pragma unroll
    for (int off = 1; off < 64; off <<= 1) m = max(m, __shfl_xor(m, off));
    cd[j] = m & 8191;                                   // code of j-th best approx
    if (k == m) k = INT_MIN;                            // retire winner (keys unique)
  }

  // ---- stage 2: exact f32/f64 re-score of 8 candidates ----
  const float* xr = x + (unsigned)row * DIM;
  const f32x4 xv = *(const f32x4*)(xr + 4 * l);         // lane owns dims 4l..4l+3
  const float t0 = -2.f * xv[0], t1 = -2.f * xv[1];
  const float t2 = -2.f * xv[2], t3 = -2.f * xv[3];

  #pragma unroll
  for (int ci = 0; ci < 8; ++ci) {
    const f32x4 e = *(const f32x4*)(embed + (unsigned)cd[ci] * DIM + 4 * l);
    float p = e[0] * (e[0] + t0);
    p = fmaf(e[1], e[1] + t1, p);
    p = fmaf(e[2], e[2] + t2, p);
    p = fmaf(e[3], e[3] + t3, p);
    sh[wave][ci][l] = p;
  }
  asm volatile("s_waitcnt lgkmcnt(0)" ::: "memory");

  // transpose-reduce: cand c = l>>3 summed by 8 lanes (sub = l&7), f64 accumulate
  const int c = l >> 3, sub = l & 7;
  const float* sp = &sh[wave][c][sub * 8];
  f32x4 v0 = *(const f32x4*)sp;
  f32x4 v1 = *(const f32x4*)(sp + 4);
  double s64 = (double)v0[0] + (double)v0[1] + (double)v0[2] + (double)v0[3]
             + (double)v1[0] + (double)v1[1] + (double)v1[2] + (double)v1[3];
  s64 += __shfl_xor(s64, 1);
  s64 += __shfl_xor(s64, 2);
  s64 += __shfl_xor(s64, 4);

  // broadcast: lane l gets score of cand (l&7)
  double sc = __shfl(s64, (l & 7) * 8);
  unsigned fkey = f2key((float)sc);
  const int myc = cd[l & 7];

  // exact top-5 within 8-lane groups (groups redundant)
  bool used = false;
  int codes[5]; float svals[5];
  #pragma unroll
  for (int j = 0; j < 5; ++j) {
    unsigned kk = used ? 0xFFFFFFFFu : fkey;
    unsigned mm = kk;
    #pragma unroll
    for (int off = 1; off < 8; off <<= 1) mm = min(mm, (unsigned)__shfl_xor((int)mm, off));
    int cc = (kk == mm) ? myc : 0x7FFFFFFF;             // ties -> lower code
    #pragma unroll
    for (int off = 1; off < 8; off <<= 1) cc = min(cc, __shfl_xor(cc, off));
    used = used || (myc == cc);
    codes[j] = cc;
    svals[j] = key2f(mm);
  }

  float ex[5], sum = 0.f;
  #pragma unroll
  for (int j = 0; j < 5; ++j) { ex[j] = expf(-(svals[j] - svals[0])); sum += ex[j]; }
  const float inv = 1.f / sum;

  if (l == 0) {
    out_idx[row] = (float)codes[0];
    #pragma unroll
    for (int j = 0; j < 5; ++j) {
      float w = ex[j] * inv;
      idx5[row * 5 + j] = codes[j];
      w5[row * 5 + j] = w;
      atomicAdd(&enc_sum[codes[j]], w);
      atomicAdd(&cnt[codes[j]], 1u);
    }
  }
}

// ============ K3: parallel scan counts -> CSR offsets, plus S factor ============
__global__ __launch_bounds__(256) void k_scan(const unsigned* __restrict__ cnt,
                                              unsigned* __restrict__ offs,
                                              unsigned* __restrict__ cursor,
                                              const float* __restrict__ enc_sum,
                                              const float* __restrict__ cluster_size,
                                              float* __restrict__ sfac) {
  __shared__ unsigned part[256];
  __shared__ double sred[256];
  const int t = threadIdx.x;
  unsigned s = 0;
  for (int i = 0; i < 32; ++i) s += cnt[t * 32 + i];
  part[t] = s;
  double ds = 0.0;
  for (int i = t; i < NCODE; i += 256)
    ds += 0.1 * (double)cluster_size[i] + 0.9 * (double)enc_sum[i];
  sred[t] = ds;
  __syncthreads();
  // Hillis-Steele inclusive scan of part[]
  #pragma unroll
  for (int off = 1; off < 256; off <<= 1) {
    unsigned v = (t >= off) ? part[t - off] : 0u;
    __syncthreads();
    part[t] += v;
    __syncthreads();
  }
  // tree-reduce sred[]
  #pragma unroll
  for (int off = 128; off; off >>= 1) {
    if (t < off) sred[t] += sred[t + off];
    __syncthreads();
  }
  if (t == 0) {
    double S = sred[0];
    sfac[0] = (float)(S / (S + (double)NCODE * 1e-5));
  }
  unsigned off0 = part[t] - s;   // exclusive prefix for this thread's 32 codes
  for (int i = 0; i < 32; ++i) {
    unsigned c = cnt[t * 32 + i];
    offs[t * 32 + i] = off0;
    cursor[t * 32 + i] = off0;
    off0 += c;
  }
}

// ============ K3b: fill CSR entries (meta = code<<16 | row) ============
__global__ __launch_bounds__(256) void k_fill(const int* __restrict__ idx5,
                                              const float* __restrict__ w5,
                                              unsigned* __restrict__ cursor,
                                              uint2* __restrict__ entries) {
  const int i = blockIdx.x * 256 + threadIdx.x;
  if (i >= NENT) return;
  const unsigned c = (unsigned)idx5[i];
  const float w = w5[i];
  const unsigned row = (unsigned)i / 5u;
  const unsigned slot = atomicAdd(&cursor[c], 1u);
  entries[slot] = make_uint2((c << 16) | row, __float_as_uint(w));
}

// ============ K4: flat segmented gather-accumulate (load-balanced) ============
__global__ __launch_bounds__(256) void k_accum2(const float* __restrict__ x,
                                                const uint2* __restrict__ entries,
                                                float* __restrict__ embsum) {
  __shared__ uint2 ent[ENT_PER_BLK];
  const int t = threadIdx.x;
  const unsigned base = blockIdx.x * ENT_PER_BLK;
  if (t < ENT_PER_BLK * 2)
    ((unsigned*)ent)[t] = ((const unsigned*)(entries + base))[t];
  __syncthreads();

  float acc = 0.f;
  unsigned cur = ent[0].x >> 16;
  #pragma unroll 8
  for (int i = 0; i < ENT_PER_BLK; ++i) {
    const uint2 e = ent[i];
    const unsigned code = e.x >> 16;
    const unsigned row = e.x & 0xFFFFu;
    const float w = __uint_as_float(e.y);
    if (code != cur) {                       // block-uniform branch
      atomicAdd(&embsum[cur * DIM + t], acc);
      acc = 0.f; cur = code;
    }
    acc = fmaf(w, x[row * DIM + t], acc);
  }
  atomicAdd(&embsum[cur * DIM + t], acc);
}

// ============ K4b: normalize embsum -> new_embed (in place) ============
__global__ __launch_bounds__(256) void k_norm(const float* __restrict__ embed_avg,
                                              const float* __restrict__ cluster_size,
                                              const float* __restrict__ enc_sum,
                                              const float* __restrict__ sfac,
                                              float* __restrict__ embsum /* -> newemb */) {
  const int k = blockIdx.x, d = threadIdx.x;
  const float ncs = 0.1f * cluster_size[k] + 0.9f * enc_sum[k];
  const float cs = (ncs + 1e-5f) * sfac[0];
  const unsigned o = (unsigned)k * DIM + d;
  embsum[o] = (0.1f * embed_avg[o] + 0.9f * embsum[o]) / cs;
}

// ============ K5: quantize = sum_j w_j * new_embed[idx_j], f32x4 wide ============
__global__ __launch_bounds__(256) void k_quant(const int* __restrict__ idx5,
                                               const float* __restrict__ w5,
                                               const float* __restrict__ newemb,
                                               float* __restrict__ out) {
  const int l = threadIdx.x & 63, wv = threadIdx.x >> 6;
  const int rb = blockIdx.x * 16;
  #pragma unroll
  for (int r = 0; r < 4; ++r) {
    const int row = rb + wv * 4 + r;
    f32x4 acc = {0.f, 0.f, 0.f, 0.f};
    #pragma unroll
    for (int j = 0; j < 5; ++j) {
      const int c = idx5[row * 5 + j];
      const float wg = w5[row * 5 + j];
      const f32x4 e = *(const f32x4*)(newemb + (unsigned)c * DIM + 4 * l);
      acc[0] = fmaf(wg, e[0], acc[0]);
      acc[1] = fmaf(wg, e[1], acc[1]);
      acc[2] = fmaf(wg, e[2], acc[2]);
      acc[3] = fmaf(wg, e[3], acc[3]);
    }
    *(f32x4*)(out + (unsigned)row * DIM + 4 * l) = acc;
  }
}

extern "C" void kernel_launch(void* const* d_in, const int* in_sizes, int n_in,
                              void* d_out, int out_size, void* d_ws, size_t ws_size,
                              hipStream_t stream) {
  const float* x            = (const float*)d_in[0];   // [65536,256]
  const float* embed        = (const float*)d_in[1];   // [8192,256]
  const float* cluster_size = (const float*)d_in[2];   // [8192]
  // d_in[3] cluster_sum unused for outputs
  const float* embed_avg    = (const float*)d_in[4];   // [8192,256]

  char* w = (char*)d_ws;
  signed char*    eswz   = (signed char*)(w + WS_ESWZ);
  int*            cinit  = (int*)(w + WS_CINIT);
  signed char*    xq     = (signed char*)(w + WS_XQ);
  int*            idx5   = (int*)(w + WS_IDX5);
  float*          w5     = (float*)(w + WS_W5);
  float*          encsum = (float*)(w + WS_ENCSUM);
  unsigned*       cnt    = (unsigned*)(w + WS_CNT);
  unsigned*       offs   = (unsigned*)(w + WS_OFFS);
  unsigned*       curs   = (unsigned*)(w + WS_CURS);
  float*          sfac   = (float*)(w + WS_SFAC);
  float*          embsum = (float*)(w + WS_NEWEMB);    // aliases xq (dead after gemm)
  uint2*          entr   = (uint2*)(w + WS_ENTR);      // aliases xq+8MB

  float* out_q   = (float*)d_out;                 // [65536*256]
  float* out_idx = out_q + (size_t)NROWS * DIM;   // [65536] as float
  int*   candk   = (int*)d_out;                   // 16MB scratch in d_out; k_quant overwrites

  // zero enc_sum + cnt (adjacent 64KB)
  hipMemsetAsync(w + WS_ENCSUM, 0, 65536, stream);

  k_prepall<<<NCODE + NROWS / 64, 256, 0, stream>>>(embed, x, eswz, cinit, xq);
  k_gemm<<<NROWS / 128 * 4, 256, 0, stream>>>(xq, eswz, cinit, candk);
  // xq dead; zero embsum (aliases xq) before accumulation
  hipMemsetAsync(w + WS_NEWEMB, 0, (size_t)NCODE * DIM * 4, stream);
  k_refine<<<NROWS / 4, 256, 0, stream>>>(x, embed, candk, out_idx, idx5, w5, encsum, cnt);
  k_scan<<<1, 256, 0, stream>>>(cnt, offs, curs, encsum, cluster_size, sfac);
  k_fill<<<(NENT + 255) / 256, 256, 0, stream>>>(idx5, w5, curs, entr);
  k_accum2<<<NENT / ENT_PER_BLK, 256, 0, stream>>>(x, entr, embsum);
  k_norm<<<NCODE, 256, 0, stream>>>(embed_avg, cluster_size, encsum, sfac, embsum);
  k_quant<<<NROWS / 16, 256, 0, stream>>>(idx5, w5, embsum, out_q);
}